// Round 3
// baseline (140.316 us; speedup 1.0000x reference)
//
#include <hip/hip_runtime.h>
#include <hip/hip_bf16.h>

// B=4, S=256, H=768, P=54.
// out[b,i,j,p] = valid ? relu(ha[b,i]+hb[b,j]+bp1) . Wp2[p] + bp2[p] : 0
// valid = cand[i] & cand[j] & i!=j; cand = (relu(x W1^T + b1) . W2[0] + b2[0]) > 0.5
// cand rate ~1% -> sparse pairs. h is ONLY used for the threshold -> the span
// gemm gates a boolean; output precision comes from the fp32 pair path.
// R3: 139.8 (split-K VALU gemm + hpart). R9: 136.8 = full-K bf16x3 MFMA span
//     gemm (hi*hi+hi*lo+lo*hi), spanPart 48KB, 4 dispatches. WORKED (-4).
// R10: R9's gemm was cvt-VALU-bound (~1100 VALU ops per K-32 step for the
//     f32->bf16 hi/lo split vs 12 MFMA; x re-split 12x, W1 16x). Hoist the
//     split into a one-shot cvt kernel (5.5MB->5.5MB packed ushort hi/lo);
//     gemm K-loop becomes pure load+MFMA. Predict span 11us -> ~3us.

#define M_ROWS 1024
#define HDIM 768
#define PDIM 54
#define MAXC 256            // candidate slot cap (actual nc ~11-27)
#define KCHUNK 16
#define NKC (HDIM / KCHUNK) // 48
#define NB_N 12             // 768/64 n-tiles

#define PAIRGRID 1024       // blocks 0..1023: zero-out + pair build
#define HABGRID  2048       // blocks 1024..3071: hab work

// ---- workspace layout (bytes) ----
#define CANDCNT_OFF  0
#define CANDIDX_OFF  8192        // MAXC int
#define CANDSLOT_OFF 12288       // 1024 int (fully written each call)
#define PAIR_OFF     16384       // up to 261120 int
#define SPAN_OFF     1064960     // spanPart, ha, hb, then bf16 hi/lo arrays

#define SPAN_BYTES   (NB_N * M_ROWS * 4)          // 49152
#define HA_BYTES     (MAXC * HDIM * 4)            // 786432
#define XCVT_SHORTS  (M_ROWS * HDIM)              // 786432 shorts = 1.5 MB
#define WCVT_SHORTS  (HDIM * HDIM)                // 589824 shorts

typedef __attribute__((ext_vector_type(8))) short short8;
typedef __attribute__((ext_vector_type(4))) float f32x4;

static __device__ __forceinline__ unsigned short f2bf(float f) {
    unsigned u = __float_as_uint(f);
    u += 0x7fffu + ((u >> 16) & 1u);
    return (unsigned short)(u >> 16);
}
static __device__ __forceinline__ float bf2f(unsigned short h) {
    return __uint_as_float(((unsigned)h) << 16);
}

// ================= one-shot f32 -> bf16 hi/lo split =================
// x (1024x768) and W1 (768x768), row-major, packed ushort. Also zeroes
// the cand/pair counters (first dispatch in the chain).
__global__ __launch_bounds__(256) void cvt_kernel(
    const float* __restrict__ x, const float* __restrict__ W1,
    unsigned short* __restrict__ xhi, unsigned short* __restrict__ xlo,
    unsigned short* __restrict__ w1hi, unsigned short* __restrict__ w1lo,
    int* __restrict__ counters)
{
    if (blockIdx.x == 0 && threadIdx.x < 2) counters[threadIdx.x] = 0;
    const int XN = XCVT_SHORTS / 4;   // float4 count for x
    const int WN = WCVT_SHORTS / 4;
    int i = blockIdx.x * 256 + threadIdx.x;
    if (i >= XN + WN) return;
    float4 v = (i < XN) ? ((const float4*)x)[i] : ((const float4*)W1)[i - XN];
    float f[4] = {v.x, v.y, v.z, v.w};
    ushort4 hi, lo;
    unsigned short h0 = f2bf(f[0]); hi.x = h0; lo.x = f2bf(f[0] - bf2f(h0));
    unsigned short h1 = f2bf(f[1]); hi.y = h1; lo.y = f2bf(f[1] - bf2f(h1));
    unsigned short h2 = f2bf(f[2]); hi.z = h2; lo.z = f2bf(f[2] - bf2f(h2));
    unsigned short h3 = f2bf(f[3]); hi.w = h3; lo.w = f2bf(f[3] - bf2f(h3));
    if (i < XN) {
        ((ushort4*)xhi)[i] = hi;
        ((ushort4*)xlo)[i] = lo;
    } else {
        ((ushort4*)w1hi)[i - XN] = hi;
        ((ushort4*)w1lo)[i - XN] = lo;
    }
}

// ================= full-K bf16x3 MFMA span gemm =================
// 64x64 tile, 4 waves (2x2), each wave 32x32 = 2x2 16x16x32 frags.
// Inputs pre-split bf16 (hi/lo): K-loop = 8 dwordx4 loads + 12 MFMA per K-32,
// zero cvt VALU. Epilogue: relu(C+b1).w2 row-reduced -> spanPart[nblk][m].
// A-frag: lane holds row m0+wseg+f*16+(l&15), k = k0+(l>>4)*8 + j (j=0..7,
// one 16B ushort8 = one 64B line per 4 lanes-group). C/D: row=(l>>4)*4+r,
// col=l&15 (m89-verified mapping).
__global__ __launch_bounds__(256) void mfma_span_kernel(
    const unsigned short* __restrict__ xhi, const unsigned short* __restrict__ xlo,
    const unsigned short* __restrict__ w1hi, const unsigned short* __restrict__ w1lo,
    const float* __restrict__ b1, const float* __restrict__ w2row,
    float* __restrict__ spanPart)
{
    const int t    = threadIdx.x;
    const int lane = t & 63;
    const int w    = t >> 6;
    const int wm   = w >> 1, wn = w & 1;
    const int l15  = lane & 15;
    const int lk   = (lane >> 4) * 8;
    const int m0   = blockIdx.x * 64;
    const int n0   = blockIdx.y * 64;

    const unsigned short* aH = xhi  + (size_t)(m0 + wm * 32 + l15) * HDIM + lk;
    const unsigned short* aL = xlo  + (size_t)(m0 + wm * 32 + l15) * HDIM + lk;
    const unsigned short* bH = w1hi + (size_t)(n0 + wn * 32 + l15) * HDIM + lk;
    const unsigned short* bL = w1lo + (size_t)(n0 + wn * 32 + l15) * HDIM + lk;

    f32x4 acc00 = {0.f, 0.f, 0.f, 0.f};
    f32x4 acc01 = {0.f, 0.f, 0.f, 0.f};
    f32x4 acc10 = {0.f, 0.f, 0.f, 0.f};
    f32x4 acc11 = {0.f, 0.f, 0.f, 0.f};

    short8 ah0_x, al0_x, ah1_x, al1_x, bh0_x, bl0_x, bh1_x, bl1_x;
    short8 ah0_y, al0_y, ah1_y, al1_y, bh0_y, bl0_y, bh1_y, bl1_y;

#define LOADK(sfx, kk) { \
    ah0##sfx = *(const short8*)(aH + (kk));             \
    al0##sfx = *(const short8*)(aL + (kk));             \
    ah1##sfx = *(const short8*)(aH + 16 * HDIM + (kk)); \
    al1##sfx = *(const short8*)(aL + 16 * HDIM + (kk)); \
    bh0##sfx = *(const short8*)(bH + (kk));             \
    bl0##sfx = *(const short8*)(bL + (kk));             \
    bh1##sfx = *(const short8*)(bH + 16 * HDIM + (kk)); \
    bl1##sfx = *(const short8*)(bL + 16 * HDIM + (kk)); \
}

#define COMPUTE(sfx) { \
    acc00 = __builtin_amdgcn_mfma_f32_16x16x32_bf16(ah0##sfx, bh0##sfx, acc00, 0, 0, 0); \
    acc00 = __builtin_amdgcn_mfma_f32_16x16x32_bf16(ah0##sfx, bl0##sfx, acc00, 0, 0, 0); \
    acc00 = __builtin_amdgcn_mfma_f32_16x16x32_bf16(al0##sfx, bh0##sfx, acc00, 0, 0, 0); \
    acc01 = __builtin_amdgcn_mfma_f32_16x16x32_bf16(ah0##sfx, bh1##sfx, acc01, 0, 0, 0); \
    acc01 = __builtin_amdgcn_mfma_f32_16x16x32_bf16(ah0##sfx, bl1##sfx, acc01, 0, 0, 0); \
    acc01 = __builtin_amdgcn_mfma_f32_16x16x32_bf16(al0##sfx, bh1##sfx, acc01, 0, 0, 0); \
    acc10 = __builtin_amdgcn_mfma_f32_16x16x32_bf16(ah1##sfx, bh0##sfx, acc10, 0, 0, 0); \
    acc10 = __builtin_amdgcn_mfma_f32_16x16x32_bf16(ah1##sfx, bl0##sfx, acc10, 0, 0, 0); \
    acc10 = __builtin_amdgcn_mfma_f32_16x16x32_bf16(al1##sfx, bh0##sfx, acc10, 0, 0, 0); \
    acc11 = __builtin_amdgcn_mfma_f32_16x16x32_bf16(ah1##sfx, bh1##sfx, acc11, 0, 0, 0); \
    acc11 = __builtin_amdgcn_mfma_f32_16x16x32_bf16(ah1##sfx, bl1##sfx, acc11, 0, 0, 0); \
    acc11 = __builtin_amdgcn_mfma_f32_16x16x32_bf16(al1##sfx, bh1##sfx, acc11, 0, 0, 0); \
}

    LOADK(_x, 0);
    for (int k = 0; k < HDIM; k += 64) {
        LOADK(_y, k + 32);
        COMPUTE(_x);
        if (k + 64 < HDIM) { LOADK(_x, k + 64); }
        COMPUTE(_y);
    }
#undef LOADK
#undef COMPUTE

    // epilogue: relu(acc + b1[n]) * w2[n], reduce over this block's 64 cols
    float sp0[4], sp1[4];
    #pragma unroll
    for (int r = 0; r < 4; ++r) { sp0[r] = 0.f; sp1[r] = 0.f; }

#define SPANACC(ACC, SP, J) { \
    _Pragma("unroll") \
    for (int r = 0; r < 4; ++r) { \
        int n = n0 + wn * 32 + (J) * 16 + l15; \
        float v = ACC[r] + b1[n]; \
        v = v > 0.f ? v : 0.f; \
        SP[r] += v * w2row[n]; \
    } \
}
    SPANACC(acc00, sp0, 0)
    SPANACC(acc01, sp0, 1)
    SPANACC(acc10, sp1, 0)
    SPANACC(acc11, sp1, 1)
#undef SPANACC

    __shared__ float red[64][2];
    #pragma unroll
    for (int r = 0; r < 4; ++r) {
        float v0 = sp0[r], v1 = sp1[r];
        #pragma unroll
        for (int msk = 1; msk < 16; msk <<= 1) {
            v0 += __shfl_xor(v0, msk, 64);
            v1 += __shfl_xor(v1, msk, 64);
        }
        if (l15 == 0) {
            int rr = (lane >> 4) * 4 + r;
            red[wm * 32 + rr][wn]      = v0;
            red[wm * 32 + 16 + rr][wn] = v1;
        }
    }
    __syncthreads();
    if (t < 64)
        spanPart[(size_t)blockIdx.y * M_ROWS + m0 + t] = red[t][0] + red[t][1];
}

// ================= candidate threshold (tiny) =================
__global__ __launch_bounds__(256) void cand_kernel(
    const float* __restrict__ spanPart, const float* __restrict__ b2,
    int* __restrict__ candCount, int* __restrict__ candIdx,
    int* __restrict__ candSlot)
{
    int m = blockIdx.x * 256 + threadIdx.x;
    float s = b2[0];
    #pragma unroll
    for (int nb = 0; nb < NB_N; ++nb) s += spanPart[(size_t)nb * M_ROWS + m];
    if (s > 0.5f) {
        int sl = atomicAdd(candCount, 1);
        if (sl < MAXC) { candIdx[sl] = m; candSlot[m] = sl; }
        else candSlot[m] = -1;
    } else {
        candSlot[m] = -1;
    }
}

// ================= merged: zero-out + pair build + hab (R8-proven) =========
__global__ __launch_bounds__(256) void hab_pairs_kernel(
    const float* __restrict__ x, const float* __restrict__ Wp1,
    const int* __restrict__ candCount, const int* __restrict__ candIdx,
    float* __restrict__ ha, float* __restrict__ hb,
    const int* __restrict__ candSlot,
    int* __restrict__ pairCount, int* __restrict__ pairList,
    float* __restrict__ out)
{
    if (blockIdx.x < PAIRGRID) {
        // ---- zero role: 256*54 floats = 3456 float4, contiguous ----
        const int pb = blockIdx.x;
        float4* dst = (float4*)(out + (size_t)pb * 256 * PDIM);
        const float4 z4 = make_float4(0.f, 0.f, 0.f, 0.f);
        for (int f = threadIdx.x; f < 256 * PDIM / 4; f += 256)
            dst[f] = z4;
        // ---- pair build ----
        int idx = pb * 256 + threadIdx.x;
        int b = idx >> 16;
        int i = (idx >> 8) & 255;
        int j = idx & 255;
        if (i != j && candSlot[b * 256 + i] >= 0 && candSlot[b * 256 + j] >= 0) {
            int p = atomicAdd(pairCount, 1);
            pairList[p] = idx;
        }
        return;
    }

    // ---- hab role ----
    __shared__ float xs[HDIM];
    __shared__ float red[2][KCHUNK][17];
    int nc = *candCount; if (nc > MAXC) nc = MAXC;
    const int nitems = nc * NKC;
    const int kk  = threadIdx.x >> 4;
    const int hb0 = (threadIdx.x & 15) * 4;

    for (int item = blockIdx.x - PAIRGRID; item < nitems; item += HABGRID) {
        int slot = item / NKC;
        int kc   = item % NKC;
        int row  = candIdx[slot];

        for (int h = threadIdx.x; h < HDIM; h += 256)
            xs[h] = x[(size_t)row * HDIM + h];
        __syncthreads();

        int k = kc * KCHUNK + kk;
        const float* wr = Wp1 + (size_t)k * (2 * HDIM);
        float sa = 0.f, sb = 0.f;
        #pragma unroll
        for (int h = hb0; h < HDIM; h += 64) {
            float4 xv = *(const float4*)(xs + h);
            float4 wa = *(const float4*)(wr + h);
            float4 wb = *(const float4*)(wr + HDIM + h);
            sa += xv.x * wa.x + xv.y * wa.y + xv.z * wa.z + xv.w * wa.w;
            sb += xv.x * wb.x + xv.y * wb.y + xv.z * wb.z + xv.w * wb.w;
        }
        red[0][kk][threadIdx.x & 15] = sa;
        red[1][kk][threadIdx.x & 15] = sb;
        __syncthreads();

        if (threadIdx.x < 32) {
            int which = threadIdx.x >> 4;
            int kk2   = threadIdx.x & 15;
            float s = 0.f;
            #pragma unroll
            for (int g = 0; g < 16; ++g) s += red[which][kk2][g];
            float* dstp = which == 0 ? ha : hb;
            dstp[(size_t)slot * HDIM + kc * KCHUNK + kk2] = s;
        }
        __syncthreads();
    }
}

// ================= sparse pair logits (R3-proven) =================
__global__ __launch_bounds__(256) void pair_kernel(
    const float* __restrict__ ha, const float* __restrict__ hb,
    const float* __restrict__ bp1, const float* __restrict__ Wp2,
    const float* __restrict__ bp2, const int* __restrict__ candSlot,
    const int* __restrict__ pairCount, const int* __restrict__ pairList,
    float* __restrict__ out)
{
    __shared__ float v[HDIM];
    __shared__ float red[4][PDIM + 2];
    const int np = *pairCount;
    const int t = threadIdx.x;
    for (int p = blockIdx.x; p < np; p += gridDim.x) {
        int idx = pairList[p];
        int b = idx >> 16;
        int i = (idx >> 8) & 255;
        int j = idx & 255;
        int si = candSlot[b * 256 + i];
        int sj = candSlot[b * 256 + j];
        if (t < 192) {
            float4 a4 = *(const float4*)(ha + (size_t)si * HDIM + t * 4);
            float4 b4 = *(const float4*)(hb + (size_t)sj * HDIM + t * 4);
            float4 c4 = *(const float4*)(bp1 + t * 4);
            float4 r;
            r.x = a4.x + b4.x + c4.x; r.x = r.x > 0.f ? r.x : 0.f;
            r.y = a4.y + b4.y + c4.y; r.y = r.y > 0.f ? r.y : 0.f;
            r.z = a4.z + b4.z + c4.z; r.z = r.z > 0.f ? r.z : 0.f;
            r.w = a4.w + b4.w + c4.w; r.w = r.w > 0.f ? r.w : 0.f;
            *(float4*)(v + t * 4) = r;
        }
        __syncthreads();
        if (t < 216) {
            int pp  = t % PDIM;
            int seg = t / PDIM;               // 0..3, h-range 192 each
            const float* w = Wp2 + (size_t)pp * HDIM + seg * 192;
            const float* vv = v + seg * 192;
            float s = 0.f;
            for (int h = 0; h < 192; h += 4) {
                float4 a = *(const float4*)(vv + h);
                float4 b2_ = *(const float4*)(w + h);
                s += a.x * b2_.x + a.y * b2_.y + a.z * b2_.z + a.w * b2_.w;
            }
            red[seg][pp] = s;
        }
        __syncthreads();
        if (t < PDIM)
            out[(size_t)idx * PDIM + t] = red[0][t] + red[1][t] + red[2][t] + red[3][t] + bp2[t];
        __syncthreads();
    }
}

extern "C" void kernel_launch(void* const* d_in, const int* in_sizes, int n_in,
                              void* d_out, int out_size, void* d_ws, size_t ws_size,
                              hipStream_t stream) {
    const float* x   = (const float*)d_in[0];
    const float* W1s = (const float*)d_in[1];
    const float* b1s = (const float*)d_in[2];
    const float* W2s = (const float*)d_in[3];
    const float* b2s = (const float*)d_in[4];
    const float* Wp1 = (const float*)d_in[5];
    const float* bp1 = (const float*)d_in[6];
    const float* Wp2 = (const float*)d_in[7];
    const float* bp2 = (const float*)d_in[8];

    char* ws = (char*)d_ws;
    int*   counters = (int*)(ws + CANDCNT_OFF);   // [0]=candCnt, [1]=pairCnt
    int*   candCnt  = counters;
    int*   pairCnt  = counters + 1;
    int*   candIdx  = (int*)(ws + CANDIDX_OFF);
    int*   candSlot = (int*)(ws + CANDSLOT_OFF);
    int*   pairList = (int*)(ws + PAIR_OFF);
    float* spanPart = (float*)(ws + SPAN_OFF);    // 12*1024 f32
    float* ha       = (float*)(ws + SPAN_OFF + SPAN_BYTES);
    float* hb       = (float*)(ws + SPAN_OFF + SPAN_BYTES + HA_BYTES);
    unsigned short* xhi  = (unsigned short*)(ws + SPAN_OFF + SPAN_BYTES + 2 * HA_BYTES);
    unsigned short* xlo  = xhi + XCVT_SHORTS;
    unsigned short* w1hi = xlo + XCVT_SHORTS;
    unsigned short* w1lo = w1hi + WCVT_SHORTS;
    float* out = (float*)d_out;

    // one-shot bf16 hi/lo split of x and W1 (+ counter zeroing)
    {
        int total4 = (XCVT_SHORTS + WCVT_SHORTS) / 4;
        int nblk = (total4 + 255) / 256;
        cvt_kernel<<<nblk, 256, 0, stream>>>(x, W1s, xhi, xlo, w1hi, w1lo, counters);
    }

    mfma_span_kernel<<<dim3(M_ROWS / 64, NB_N), 256, 0, stream>>>(
        xhi, xlo, w1hi, w1lo, b1s, W2s, spanPart);

    cand_kernel<<<4, 256, 0, stream>>>(spanPart, b2s, candCnt, candIdx, candSlot);

    hab_pairs_kernel<<<PAIRGRID + HABGRID, 256, 0, stream>>>(
        x, Wp1, candCnt, candIdx, ha, hb, candSlot, pairCnt, pairList, out);

    pair_kernel<<<512, 256, 0, stream>>>(ha, hb, bp1, Wp2, bp2,
                                         candSlot, pairCnt, pairList, out);
}

// Round 4
// 132.975 us; speedup vs baseline: 1.0552x; 1.0552x over previous
//
#include <hip/hip_runtime.h>
#include <hip/hip_bf16.h>

// B=4, S=256, H=768, P=54.
// out[b,i,j,p] = valid ? relu(ha[b,i]+hb[b,j]+bp1) . Wp2[p] + bp2[p] : 0
// valid = cand[i] & cand[j] & i!=j; cand = (relu(x W1^T + b1) . W2[0] + b2[0]) > 0.5
// cand rate ~1% -> sparse pairs. h is ONLY used for the threshold -> the span
// gemm gates a boolean; output precision comes from the fp32 pair path.
// R3: 139.8 (split-K VALU gemm + hpart). R9: 136.8 BEST = full-K bf16x3 MFMA
//     span gemm (hi*hi+hi*lo+lo*hi in-loop cvt), spanPart 48KB, 4 dispatches.
// R10: cvt-hoist to a pre-split kernel = 140.3 REGRESSION. Post-mortem: R9's
//     in-loop cvt is only ~320 VALU/step and hides load latency; at 192 blocks
//     the gemm is 1 wave/SIMD, so R10 just swapped VALU-bound for exposed-
//     latency-bound (wash) and paid +2us cvt + 1 dispatch.
// R11: revert to R9 verbatim (single lever: remove the R10 regression).
// Floor model: span ~4-5us, cand ~1, k4 ~9.4us (56.6MB out-zero at ~6.1TB/s,
//     hab's 127MB L2 traffic hides under it), pair ~2, + gaps. Remaining
//     addressable slack ~1.5-2us < +/-2us noise. Harness-fixed ~120us
//     (268MB poison fills at 44us each are the only top-5 dispatches).

#define M_ROWS 1024
#define HDIM 768
#define PDIM 54
#define MAXC 256            // candidate slot cap (actual nc ~11-27)
#define KCHUNK 16
#define NKC (HDIM / KCHUNK) // 48
#define NB_N 12             // 768/64 n-tiles

#define PAIRGRID 1024       // blocks 0..1023: zero-out + pair build
#define HABGRID  2048       // blocks 1024..3071: hab work

// ---- workspace layout (bytes) ----
#define CANDCNT_OFF  0
#define CANDIDX_OFF  8192        // MAXC int
#define CANDSLOT_OFF 12288       // 1024 int (fully written each call)
#define PAIR_OFF     16384       // up to 261120 int
#define SPAN_OFF     1064960     // 12*1024 f32 spanPart, then ha, hb

typedef __attribute__((ext_vector_type(8))) short short8;
typedef __attribute__((ext_vector_type(4))) float f32x4;

static __device__ __forceinline__ unsigned short f2bf(float f) {
    unsigned u = __float_as_uint(f);
    u += 0x7fffu + ((u >> 16) & 1u);
    return (unsigned short)(u >> 16);
}
static __device__ __forceinline__ float bf2f(unsigned short h) {
    return __uint_as_float(((unsigned)h) << 16);
}
static __device__ __forceinline__ void cvt8(float4 p, float4 q,
                                            short8& hi, short8& lo) {
    float f[8] = {p.x, p.y, p.z, p.w, q.x, q.y, q.z, q.w};
    #pragma unroll
    for (int j = 0; j < 8; ++j) {
        unsigned short h = f2bf(f[j]);
        hi[j] = (short)h;
        lo[j] = (short)f2bf(f[j] - bf2f(h));
    }
}

// ================= full-K bf16x3 MFMA span gemm =================
// 64x64 tile, 4 waves (2x2), each wave 32x32 = 2x2 16x16x32 frags.
// C[m][n] = sum_k x[m][k]*W1[n][k]; epilogue: relu(C+b1).w2 row-reduced
// -> spanPart[nblk][m]. Register-double-buffered K loop (24 steps of 32).
// A-frag: lane holds x[row=m0+wseg+f*16+(l&15)][k0+(l>>4)*8 + j], j=0..7.
// B-frag: same pattern on W1 rows (B^T layout). C/D: row=(l>>4)*4+r, col=l&15.
__global__ __launch_bounds__(256) void mfma_span_kernel(
    const float* __restrict__ x, const float* __restrict__ W1,
    const float* __restrict__ b1, const float* __restrict__ w2row,
    float* __restrict__ spanPart, int* __restrict__ counters)
{
    if (blockIdx.x == 0 && blockIdx.y == 0 && threadIdx.x < 2)
        counters[threadIdx.x] = 0;

    const int t    = threadIdx.x;
    const int lane = t & 63;
    const int w    = t >> 6;
    const int wm   = w >> 1, wn = w & 1;
    const int l15  = lane & 15;
    const int lk   = (lane >> 4) * 8;
    const int m0   = blockIdx.x * 64;
    const int n0   = blockIdx.y * 64;

    const float* aBase = x  + (size_t)(m0 + wm * 32 + l15) * HDIM + lk;
    const float* bBase = W1 + (size_t)(n0 + wn * 32 + l15) * HDIM + lk;

    f32x4 acc00 = {0.f, 0.f, 0.f, 0.f};
    f32x4 acc01 = {0.f, 0.f, 0.f, 0.f};
    f32x4 acc10 = {0.f, 0.f, 0.f, 0.f};
    f32x4 acc11 = {0.f, 0.f, 0.f, 0.f};

    float4 ra0p_x, ra0q_x, ra1p_x, ra1q_x, rb0p_x, rb0q_x, rb1p_x, rb1q_x;
    float4 ra0p_y, ra0q_y, ra1p_y, ra1q_y, rb0p_y, rb0q_y, rb1p_y, rb1q_y;

#define LOADK(sfx, kk) { \
    ra0p##sfx = *(const float4*)(aBase + (kk));                 \
    ra0q##sfx = *(const float4*)(aBase + (kk) + 4);             \
    ra1p##sfx = *(const float4*)(aBase + 16 * HDIM + (kk));     \
    ra1q##sfx = *(const float4*)(aBase + 16 * HDIM + (kk) + 4); \
    rb0p##sfx = *(const float4*)(bBase + (kk));                 \
    rb0q##sfx = *(const float4*)(bBase + (kk) + 4);             \
    rb1p##sfx = *(const float4*)(bBase + 16 * HDIM + (kk));     \
    rb1q##sfx = *(const float4*)(bBase + 16 * HDIM + (kk) + 4); \
}

#define COMPUTE(sfx) { \
    short8 ah0, al0, ah1, al1, bh0, bl0, bh1, bl1;  \
    cvt8(ra0p##sfx, ra0q##sfx, ah0, al0);           \
    cvt8(ra1p##sfx, ra1q##sfx, ah1, al1);           \
    cvt8(rb0p##sfx, rb0q##sfx, bh0, bl0);           \
    cvt8(rb1p##sfx, rb1q##sfx, bh1, bl1);           \
    acc00 = __builtin_amdgcn_mfma_f32_16x16x32_bf16(ah0, bh0, acc00, 0, 0, 0); \
    acc00 = __builtin_amdgcn_mfma_f32_16x16x32_bf16(ah0, bl0, acc00, 0, 0, 0); \
    acc00 = __builtin_amdgcn_mfma_f32_16x16x32_bf16(al0, bh0, acc00, 0, 0, 0); \
    acc01 = __builtin_amdgcn_mfma_f32_16x16x32_bf16(ah0, bh1, acc01, 0, 0, 0); \
    acc01 = __builtin_amdgcn_mfma_f32_16x16x32_bf16(ah0, bl1, acc01, 0, 0, 0); \
    acc01 = __builtin_amdgcn_mfma_f32_16x16x32_bf16(al0, bh1, acc01, 0, 0, 0); \
    acc10 = __builtin_amdgcn_mfma_f32_16x16x32_bf16(ah1, bh0, acc10, 0, 0, 0); \
    acc10 = __builtin_amdgcn_mfma_f32_16x16x32_bf16(ah1, bl0, acc10, 0, 0, 0); \
    acc10 = __builtin_amdgcn_mfma_f32_16x16x32_bf16(al1, bh0, acc10, 0, 0, 0); \
    acc11 = __builtin_amdgcn_mfma_f32_16x16x32_bf16(ah1, bh1, acc11, 0, 0, 0); \
    acc11 = __builtin_amdgcn_mfma_f32_16x16x32_bf16(ah1, bl1, acc11, 0, 0, 0); \
    acc11 = __builtin_amdgcn_mfma_f32_16x16x32_bf16(al1, bh1, acc11, 0, 0, 0); \
}

    LOADK(_x, 0);
    for (int k = 0; k < HDIM; k += 64) {
        LOADK(_y, k + 32);
        COMPUTE(_x);
        if (k + 64 < HDIM) { LOADK(_x, k + 64); }
        COMPUTE(_y);
    }
#undef LOADK
#undef COMPUTE

    // epilogue: relu(acc + b1[n]) * w2[n], reduce over this block's 64 cols
    float sp0[4], sp1[4];
    #pragma unroll
    for (int r = 0; r < 4; ++r) { sp0[r] = 0.f; sp1[r] = 0.f; }

#define SPANACC(ACC, SP, J) { \
    _Pragma("unroll") \
    for (int r = 0; r < 4; ++r) { \
        int n = n0 + wn * 32 + (J) * 16 + l15; \
        float v = ACC[r] + b1[n]; \
        v = v > 0.f ? v : 0.f; \
        SP[r] += v * w2row[n]; \
    } \
}
    SPANACC(acc00, sp0, 0)
    SPANACC(acc01, sp0, 1)
    SPANACC(acc10, sp1, 0)
    SPANACC(acc11, sp1, 1)
#undef SPANACC

    __shared__ float red[64][2];
    #pragma unroll
    for (int r = 0; r < 4; ++r) {
        float v0 = sp0[r], v1 = sp1[r];
        #pragma unroll
        for (int msk = 1; msk < 16; msk <<= 1) {
            v0 += __shfl_xor(v0, msk, 64);
            v1 += __shfl_xor(v1, msk, 64);
        }
        if (l15 == 0) {
            int rr = (lane >> 4) * 4 + r;
            red[wm * 32 + rr][wn]      = v0;
            red[wm * 32 + 16 + rr][wn] = v1;
        }
    }
    __syncthreads();
    if (t < 64)
        spanPart[(size_t)blockIdx.y * M_ROWS + m0 + t] = red[t][0] + red[t][1];
}

// ================= candidate threshold (tiny) =================
__global__ __launch_bounds__(256) void cand_kernel(
    const float* __restrict__ spanPart, const float* __restrict__ b2,
    int* __restrict__ candCount, int* __restrict__ candIdx,
    int* __restrict__ candSlot)
{
    int m = blockIdx.x * 256 + threadIdx.x;
    float s = b2[0];
    #pragma unroll
    for (int nb = 0; nb < NB_N; ++nb) s += spanPart[(size_t)nb * M_ROWS + m];
    if (s > 0.5f) {
        int sl = atomicAdd(candCount, 1);
        if (sl < MAXC) { candIdx[sl] = m; candSlot[m] = sl; }
        else candSlot[m] = -1;
    } else {
        candSlot[m] = -1;
    }
}

// ================= merged: zero-out + pair build + hab (R8-proven) =========
__global__ __launch_bounds__(256) void hab_pairs_kernel(
    const float* __restrict__ x, const float* __restrict__ Wp1,
    const int* __restrict__ candCount, const int* __restrict__ candIdx,
    float* __restrict__ ha, float* __restrict__ hb,
    const int* __restrict__ candSlot,
    int* __restrict__ pairCount, int* __restrict__ pairList,
    float* __restrict__ out)
{
    if (blockIdx.x < PAIRGRID) {
        // ---- zero role: 256*54 floats = 3456 float4, contiguous ----
        const int pb = blockIdx.x;
        float4* dst = (float4*)(out + (size_t)pb * 256 * PDIM);
        const float4 z4 = make_float4(0.f, 0.f, 0.f, 0.f);
        for (int f = threadIdx.x; f < 256 * PDIM / 4; f += 256)
            dst[f] = z4;
        // ---- pair build ----
        int idx = pb * 256 + threadIdx.x;
        int b = idx >> 16;
        int i = (idx >> 8) & 255;
        int j = idx & 255;
        if (i != j && candSlot[b * 256 + i] >= 0 && candSlot[b * 256 + j] >= 0) {
            int p = atomicAdd(pairCount, 1);
            pairList[p] = idx;
        }
        return;
    }

    // ---- hab role ----
    __shared__ float xs[HDIM];
    __shared__ float red[2][KCHUNK][17];
    int nc = *candCount; if (nc > MAXC) nc = MAXC;
    const int nitems = nc * NKC;
    const int kk  = threadIdx.x >> 4;
    const int hb0 = (threadIdx.x & 15) * 4;

    for (int item = blockIdx.x - PAIRGRID; item < nitems; item += HABGRID) {
        int slot = item / NKC;
        int kc   = item % NKC;
        int row  = candIdx[slot];

        for (int h = threadIdx.x; h < HDIM; h += 256)
            xs[h] = x[(size_t)row * HDIM + h];
        __syncthreads();

        int k = kc * KCHUNK + kk;
        const float* wr = Wp1 + (size_t)k * (2 * HDIM);
        float sa = 0.f, sb = 0.f;
        #pragma unroll
        for (int h = hb0; h < HDIM; h += 64) {
            float4 xv = *(const float4*)(xs + h);
            float4 wa = *(const float4*)(wr + h);
            float4 wb = *(const float4*)(wr + HDIM + h);
            sa += xv.x * wa.x + xv.y * wa.y + xv.z * wa.z + xv.w * wa.w;
            sb += xv.x * wb.x + xv.y * wb.y + xv.z * wb.z + xv.w * wb.w;
        }
        red[0][kk][threadIdx.x & 15] = sa;
        red[1][kk][threadIdx.x & 15] = sb;
        __syncthreads();

        if (threadIdx.x < 32) {
            int which = threadIdx.x >> 4;
            int kk2   = threadIdx.x & 15;
            float s = 0.f;
            #pragma unroll
            for (int g = 0; g < 16; ++g) s += red[which][kk2][g];
            float* dstp = which == 0 ? ha : hb;
            dstp[(size_t)slot * HDIM + kc * KCHUNK + kk2] = s;
        }
        __syncthreads();
    }
}

// ================= sparse pair logits (R3-proven) =================
__global__ __launch_bounds__(256) void pair_kernel(
    const float* __restrict__ ha, const float* __restrict__ hb,
    const float* __restrict__ bp1, const float* __restrict__ Wp2,
    const float* __restrict__ bp2, const int* __restrict__ candSlot,
    const int* __restrict__ pairCount, const int* __restrict__ pairList,
    float* __restrict__ out)
{
    __shared__ float v[HDIM];
    __shared__ float red[4][PDIM + 2];
    const int np = *pairCount;
    const int t = threadIdx.x;
    for (int p = blockIdx.x; p < np; p += gridDim.x) {
        int idx = pairList[p];
        int b = idx >> 16;
        int i = (idx >> 8) & 255;
        int j = idx & 255;
        int si = candSlot[b * 256 + i];
        int sj = candSlot[b * 256 + j];
        if (t < 192) {
            float4 a4 = *(const float4*)(ha + (size_t)si * HDIM + t * 4);
            float4 b4 = *(const float4*)(hb + (size_t)sj * HDIM + t * 4);
            float4 c4 = *(const float4*)(bp1 + t * 4);
            float4 r;
            r.x = a4.x + b4.x + c4.x; r.x = r.x > 0.f ? r.x : 0.f;
            r.y = a4.y + b4.y + c4.y; r.y = r.y > 0.f ? r.y : 0.f;
            r.z = a4.z + b4.z + c4.z; r.z = r.z > 0.f ? r.z : 0.f;
            r.w = a4.w + b4.w + c4.w; r.w = r.w > 0.f ? r.w : 0.f;
            *(float4*)(v + t * 4) = r;
        }
        __syncthreads();
        if (t < 216) {
            int pp  = t % PDIM;
            int seg = t / PDIM;               // 0..3, h-range 192 each
            const float* w = Wp2 + (size_t)pp * HDIM + seg * 192;
            const float* vv = v + seg * 192;
            float s = 0.f;
            for (int h = 0; h < 192; h += 4) {
                float4 a = *(const float4*)(vv + h);
                float4 b2_ = *(const float4*)(w + h);
                s += a.x * b2_.x + a.y * b2_.y + a.z * b2_.z + a.w * b2_.w;
            }
            red[seg][pp] = s;
        }
        __syncthreads();
        if (t < PDIM)
            out[(size_t)idx * PDIM + t] = red[0][t] + red[1][t] + red[2][t] + red[3][t] + bp2[t];
        __syncthreads();
    }
}

extern "C" void kernel_launch(void* const* d_in, const int* in_sizes, int n_in,
                              void* d_out, int out_size, void* d_ws, size_t ws_size,
                              hipStream_t stream) {
    const float* x   = (const float*)d_in[0];
    const float* W1s = (const float*)d_in[1];
    const float* b1s = (const float*)d_in[2];
    const float* W2s = (const float*)d_in[3];
    const float* b2s = (const float*)d_in[4];
    const float* Wp1 = (const float*)d_in[5];
    const float* bp1 = (const float*)d_in[6];
    const float* Wp2 = (const float*)d_in[7];
    const float* bp2 = (const float*)d_in[8];

    char* ws = (char*)d_ws;
    int*   counters = (int*)(ws + CANDCNT_OFF);   // [0]=candCnt, [1]=pairCnt
    int*   candCnt  = counters;
    int*   pairCnt  = counters + 1;
    int*   candIdx  = (int*)(ws + CANDIDX_OFF);
    int*   candSlot = (int*)(ws + CANDSLOT_OFF);
    int*   pairList = (int*)(ws + PAIR_OFF);
    float* spanPart = (float*)(ws + SPAN_OFF);    // 12*1024 f32
    float* ha       = spanPart + (size_t)NB_N * M_ROWS;
    float* hb       = ha + (size_t)MAXC * HDIM;
    float* out = (float*)d_out;

    mfma_span_kernel<<<dim3(M_ROWS / 64, NB_N), 256, 0, stream>>>(
        x, W1s, b1s, W2s, spanPart, counters);

    cand_kernel<<<4, 256, 0, stream>>>(spanPart, b2s, candCnt, candIdx, candSlot);

    hab_pairs_kernel<<<PAIRGRID + HABGRID, 256, 0, stream>>>(
        x, Wp1, candCnt, candIdx, ha, hb, candSlot, pairCnt, pairList, out);

    pair_kernel<<<512, 256, 0, stream>>>(ha, hb, bp1, Wp2, bp2,
                                         candSlot, pairCnt, pairList, out);
}